// Round 6
// baseline (349.326 us; speedup 1.0000x reference)
//
#include <hip/hip_runtime.h>

#define NEG_SLOPE 0.2f
#define EPSV 1e-16f

typedef float f32x4 __attribute__((ext_vector_type(4)));

// Monotone f32 <-> u32 mapping so atomicMax(u32) implements float max.
__device__ __forceinline__ unsigned fenc(float f) {
    unsigned b = __float_as_uint(f);
    return b ^ ((b & 0x80000000u) ? 0xFFFFFFFFu : 0x80000000u);
}
__device__ __forceinline__ float fdec(unsigned u) {
    unsigned b = (u & 0x80000000u) ? (u ^ 0x80000000u) : ~u;
    return __uint_as_float(b);
}
#define FENC_NEG_INF 0x007FFFFFu   // fenc(-inf)

// Detect int64 vs int32 edge_index on device.
__global__ void detect_idx_kernel(const unsigned* __restrict__ ei32,
                                  int* __restrict__ flag) {
    __shared__ int anynz;
    if (threadIdx.x == 0) anynz = 0;
    __syncthreads();
    unsigned v = ei32[2 * threadIdx.x + 1];
    if (v != 0u) anynz = 1;
    __syncthreads();
    if (threadIdx.x == 0) *flag = (anynz ? 0 : 1);   // 1 => int64
}

__device__ __forceinline__ void load_edge(const void* ei, int is64, int E,
                                          int e, int& trg, int& src) {
    if (is64) {
        const long long* p = (const long long*)ei;
        trg = (int)__builtin_nontemporal_load(&p[e]);
        src = (int)__builtin_nontemporal_load(&p[(size_t)E + e]);
    } else {
        const int* p = (const int*)ei;
        trg = __builtin_nontemporal_load(&p[e]);
        src = __builtin_nontemporal_load(&p[E + e]);
    }
}
__device__ __forceinline__ int load_trg(const void* ei, int is64, int e) {
    if (is64) return (int)__builtin_nontemporal_load(&((const long long*)ei)[e]);
    return __builtin_nontemporal_load(&((const int*)ei)[e]);
}

// K1: per-node logits per head; zero all nsum replicas; init global-max slot.
__global__ void node_scores_kernel(const float* __restrict__ nf,
                                   const float* __restrict__ sfs,
                                   const float* __restrict__ sft,
                                   float* __restrict__ ss,
                                   float* __restrict__ st,
                                   float* __restrict__ nsum,
                                   unsigned* __restrict__ gmax,
                                   int NH, int R) {
    int i = blockIdx.x * blockDim.x + threadIdx.x;
    if (i >= NH) return;
    if (i == 0) *gmax = FENC_NEG_INF;
    for (int r = 0; r < R; ++r) nsum[(size_t)r * NH + i] = 0.f;
    int h = i & 3;
    const float4* __restrict__ row = (const float4*)(nf + (size_t)i * 32);
    const float4* __restrict__ as  = (const float4*)(sfs + h * 32);
    const float4* __restrict__ at  = (const float4*)(sft + h * 32);
    float accs = 0.f, acct = 0.f;
#pragma unroll
    for (int q = 0; q < 8; ++q) {
        float4 v = row[q];
        float4 a = as[q];
        float4 b = at[q];
        accs += v.x * a.x + v.y * a.y + v.z * a.z + v.w * a.w;
        acct += v.x * b.x + v.y * b.y + v.z * b.z + v.w * b.w;
    }
    ss[i] = accs;
    st[i] = acct;
}

// ---------- lean pipeline ----------
// Algebra: exp(lr-c)/(sum exp(lr-c) + eps) == exp(lr)/(sum exp(lr) + eps*exp(c)).
// So the sum pass needs NO global max; c is only needed in the final divide.
// K2: one thread per edge: p[h]=exp(lr[h]) -> pbuf (nt, float4), scatter-add
// into this block's nsum replica (contention / R), track running max.
__global__ void edge_fused_kernel(const void* __restrict__ ei,
                                  const int* __restrict__ flag,
                                  const float* __restrict__ ss,
                                  const float* __restrict__ st,
                                  float* __restrict__ pbuf,
                                  float* __restrict__ nsum,
                                  unsigned* __restrict__ gmax,
                                  int E, int NH, int R) {
    __shared__ float red[256];
    int is64 = *flag;
    int stride = gridDim.x * blockDim.x;
    float* __restrict__ ns = nsum + (size_t)(blockIdx.x & (R - 1)) * NH;
    float lmax = -__builtin_inff();
    for (int e = blockIdx.x * blockDim.x + threadIdx.x; e < E; e += stride) {
        int trg, src;
        load_edge(ei, is64, E, e, trg, src);
        f32x4 a = *(const f32x4*)(ss + (size_t)src * 4);
        f32x4 b = *(const f32x4*)(st + (size_t)trg * 4);
        f32x4 s = a + b;
        f32x4 p;
#pragma unroll
        for (int h = 0; h < 4; ++h) {
            float lr = s[h] > 0.f ? s[h] : NEG_SLOPE * s[h];
            lmax = fmaxf(lmax, lr);
            p[h] = __expf(lr);
        }
        __builtin_nontemporal_store(p, (f32x4*)(pbuf + (size_t)e * 4));
#pragma unroll
        for (int h = 0; h < 4; ++h) atomicAdd(&ns[(size_t)trg * 4 + h], p[h]);
    }
    red[threadIdx.x] = lmax;
    __syncthreads();
    for (int off = 128; off > 0; off >>= 1) {
        if (threadIdx.x < off)
            red[threadIdx.x] = fmaxf(red[threadIdx.x], red[threadIdx.x + off]);
        __syncthreads();
    }
    if (threadIdx.x == 0) atomicMax(gmax, fenc(red[0]));
}

// K2b: fold replicas: nsum[0][i] += nsum[1..R-1][i]  (float4 per thread).
__global__ void fold_kernel(float* __restrict__ nsum, int N4, int NH, int R) {
    int i = blockIdx.x * blockDim.x + threadIdx.x;
    if (i >= N4) return;
    f32x4 a = ((f32x4*)nsum)[i];
    for (int r = 1; r < R; ++r)
        a += *(const f32x4*)(nsum + (size_t)r * NH + (size_t)i * 4);
    ((f32x4*)nsum)[i] = a;
}

// K3: att = p / (nsum[trg] + eps*exp(c)); float4 in, float4 nt out.
__global__ void att_lean_kernel(const void* __restrict__ ei,
                                const int* __restrict__ flag,
                                const float* __restrict__ pbuf,
                                const float* __restrict__ nsum,
                                const unsigned* __restrict__ gmax,
                                float* __restrict__ out,
                                int E) {
    int is64 = *flag;
    float de = EPSV * __expf(fdec(*gmax));
    int stride = gridDim.x * blockDim.x;
    for (int e = blockIdx.x * blockDim.x + threadIdx.x; e < E; e += stride) {
        int trg = load_trg(ei, is64, e);
        f32x4 p = __builtin_nontemporal_load((const f32x4*)(pbuf + (size_t)e * 4));
        f32x4 d = *(const f32x4*)(nsum + (size_t)trg * 4);
        f32x4 a = p / (d + de);
        __builtin_nontemporal_store(a, (f32x4*)(out + (size_t)e * 4));
    }
}

// ---------- fallback (ws too small): r3-style recompute, single nsum ----------
__device__ __forceinline__ float edge_lr_rc(const void* ei, int is64,
                                            const float* ss, const float* st,
                                            int E, int e, int h, int* trg_out) {
    int trg, src;
    load_edge(ei, is64, E, e, trg, src);
    if (trg_out) *trg_out = trg;
    float s = ss[src * 4 + h] + st[trg * 4 + h];
    return s > 0.f ? s : NEG_SLOPE * s;
}

__global__ void edge_max_fb_kernel(const void* __restrict__ ei,
                                   const int* __restrict__ flag,
                                   const float* __restrict__ ss,
                                   const float* __restrict__ st,
                                   unsigned* __restrict__ gmax, int E) {
    __shared__ float red[256];
    int is64 = *flag;
    int i = blockIdx.x * blockDim.x + threadIdx.x;
    float lr = -__builtin_inff();
    if (i < E * 4) lr = edge_lr_rc(ei, is64, ss, st, E, i >> 2, i & 3, nullptr);
    red[threadIdx.x] = lr;
    __syncthreads();
    for (int off = 128; off > 0; off >>= 1) {
        if (threadIdx.x < off)
            red[threadIdx.x] = fmaxf(red[threadIdx.x], red[threadIdx.x + off]);
        __syncthreads();
    }
    if (threadIdx.x == 0) atomicMax(gmax, fenc(red[0]));
}

__global__ void edge_exp_sum_fb_kernel(const void* __restrict__ ei,
                                       const int* __restrict__ flag,
                                       const float* __restrict__ ss,
                                       const float* __restrict__ st,
                                       const unsigned* __restrict__ gmax,
                                       float* __restrict__ nsum, int E) {
    int i = blockIdx.x * blockDim.x + threadIdx.x;
    if (i >= E * 4) return;
    int is64 = *flag;
    float c = fdec(*gmax);
    int trg;
    float lr = edge_lr_rc(ei, is64, ss, st, E, i >> 2, i & 3, &trg);
    atomicAdd(&nsum[trg * 4 + (i & 3)], __expf(lr - c));
}

__global__ void att_fb_kernel(const void* __restrict__ ei,
                              const int* __restrict__ flag,
                              const float* __restrict__ ss,
                              const float* __restrict__ st,
                              const unsigned* __restrict__ gmax,
                              const float* __restrict__ nsum,
                              float* __restrict__ out, int E) {
    int i = blockIdx.x * blockDim.x + threadIdx.x;
    if (i >= E * 4) return;
    int is64 = *flag;
    float c = fdec(*gmax);
    int trg;
    float lr = edge_lr_rc(ei, is64, ss, st, E, i >> 2, i & 3, &trg);
    float a = __expf(lr - c) / (nsum[trg * 4 + (i & 3)] + EPSV);
    __builtin_nontemporal_store(a, &out[i]);
}

// K5: feature gather; 32 lanes x 16B = 512B per edge, nt stores.
__global__ void gather_feat_kernel(const void* __restrict__ ei,
                                   const int* __restrict__ flag,
                                   const f32x4* __restrict__ nf4,
                                   f32x4* __restrict__ out4,
                                   int E) {
    int is64 = *flag;
    int n = E * 32;
    int stride = gridDim.x * blockDim.x;
    for (int t = blockIdx.x * blockDim.x + threadIdx.x; t < n; t += stride) {
        int e = t >> 5, q = t & 31;
        int src;
        if (is64) {
            src = (int)__builtin_nontemporal_load(&((const long long*)ei)[(size_t)E + e]);
        } else {
            src = __builtin_nontemporal_load(&((const int*)ei)[E + e]);
        }
        f32x4 v = nf4[(size_t)src * 32 + q];
        __builtin_nontemporal_store(v, &out4[(size_t)e * 32 + q]);
    }
}

extern "C" void kernel_launch(void* const* d_in, const int* in_sizes, int n_in,
                              void* d_out, int out_size, void* d_ws, size_t ws_size,
                              hipStream_t stream) {
    const float* nf  = (const float*)d_in[0];
    const float* sfs = (const float*)d_in[1];
    const float* sft = (const float*)d_in[2];
    const void*  ei  = d_in[3];

    const int NH = in_sizes[0] / 32;   // N*H (F = 32)
    const int E  = in_sizes[3] / 2;

    float* out = (float*)d_out;
    float* ws  = (float*)d_ws;
    // Layout: ss[NH] | st[NH] | flag,gmax,pad,pad | pbuf[E*4] | nsum[R*NH]
    float*    ss    = ws;
    float*    st    = ws + NH;
    int*      flag  = (int*)(ws + 2 * (size_t)NH);
    unsigned* gmax  = (unsigned*)(flag + 1);
    float*    pbuf  = ws + 2 * (size_t)NH + 4;
    float*    nsum  = pbuf + (size_t)E * 4;

    // Pick largest power-of-two replica count R that fits in ws.
    int R = 0;
    for (int r = 8; r >= 1; r >>= 1) {
        size_t need = ((size_t)2 * NH + 4 + (size_t)E * 4 + (size_t)r * NH) * 4;
        if (ws_size >= need) { R = r; break; }
    }

    const int B = 256;

    detect_idx_kernel<<<1, 256, 0, stream>>>((const unsigned*)ei, flag);

    if (R > 0) {
        node_scores_kernel<<<(NH + B - 1) / B, B, 0, stream>>>(nf, sfs, sft, ss, st,
                                                               nsum, gmax, NH, R);
        edge_fused_kernel<<<2048, B, 0, stream>>>(ei, flag, ss, st, pbuf, nsum,
                                                  gmax, E, NH, R);
        if (R > 1) {
            int N4 = NH / 4;
            fold_kernel<<<(N4 + B - 1) / B, B, 0, stream>>>(nsum, N4, NH, R);
        }
        att_lean_kernel<<<2048, B, 0, stream>>>(ei, flag, pbuf, nsum, gmax, out, E);
    } else {
        // minimal-ws fallback: nsum lives right after gmax
        float* nsum_fb = (float*)(gmax + 1);
        node_scores_kernel<<<(NH + B - 1) / B, B, 0, stream>>>(nf, sfs, sft, ss, st,
                                                               nsum_fb, gmax, NH, 1);
        int n4 = E * 4;
        edge_max_fb_kernel<<<(n4 + B - 1) / B, B, 0, stream>>>(ei, flag, ss, st, gmax, E);
        edge_exp_sum_fb_kernel<<<(n4 + B - 1) / B, B, 0, stream>>>(ei, flag, ss, st,
                                                                   gmax, nsum_fb, E);
        att_fb_kernel<<<(n4 + B - 1) / B, B, 0, stream>>>(ei, flag, ss, st, gmax,
                                                          nsum_fb, out, E);
    }

    gather_feat_kernel<<<4096, B, 0, stream>>>(
        ei, flag, (const f32x4*)nf, (f32x4*)(out + (size_t)E * 4), E);
}

// Round 7
// 284.500 us; speedup vs baseline: 1.2279x; 1.2279x over previous
//
#include <hip/hip_runtime.h>

#define NEG_SLOPE 0.2f
#define EPSV 1e-16f

typedef float f32x4 __attribute__((ext_vector_type(4)));

// Monotone f32 <-> u32 mapping so atomicMax(u32) implements float max.
__device__ __forceinline__ unsigned fenc(float f) {
    unsigned b = __float_as_uint(f);
    return b ^ ((b & 0x80000000u) ? 0xFFFFFFFFu : 0x80000000u);
}
__device__ __forceinline__ float fdec(unsigned u) {
    unsigned b = (u & 0x80000000u) ? (u ^ 0x80000000u) : ~u;
    return __uint_as_float(b);
}
#define FENC_NEG_INF 0x007FFFFFu   // fenc(-inf)

// Detect int64 vs int32 edge_index on device.
__global__ void detect_idx_kernel(const unsigned* __restrict__ ei32,
                                  int* __restrict__ flag) {
    __shared__ int anynz;
    if (threadIdx.x == 0) anynz = 0;
    __syncthreads();
    unsigned v = ei32[2 * threadIdx.x + 1];
    if (v != 0u) anynz = 1;
    __syncthreads();
    if (threadIdx.x == 0) *flag = (anynz ? 0 : 1);   // 1 => int64
}

__device__ __forceinline__ int load_idx(const void* ei, int is64, size_t k) {
    if (is64) return (int)__builtin_nontemporal_load(&((const long long*)ei)[k]);
    return __builtin_nontemporal_load(&((const int*)ei)[k]);
}

// K1: per-node logits per head; zero nsum; init global-max slot.
__global__ void node_scores_kernel(const float* __restrict__ nf,
                                   const float* __restrict__ sfs,
                                   const float* __restrict__ sft,
                                   float* __restrict__ ss,
                                   float* __restrict__ st,
                                   float* __restrict__ nsum,
                                   unsigned* __restrict__ gmax,
                                   int NH) {
    int i = blockIdx.x * blockDim.x + threadIdx.x;
    if (i >= NH) return;
    if (i == 0) *gmax = FENC_NEG_INF;
    nsum[i] = 0.f;
    int h = i & 3;
    const float4* __restrict__ row = (const float4*)(nf + (size_t)i * 32);
    const float4* __restrict__ as  = (const float4*)(sfs + h * 32);
    const float4* __restrict__ at  = (const float4*)(sft + h * 32);
    float accs = 0.f, acct = 0.f;
#pragma unroll
    for (int q = 0; q < 8; ++q) {
        float4 v = row[q];
        float4 a = as[q];
        float4 b = at[q];
        accs += v.x * a.x + v.y * a.y + v.z * a.z + v.w * a.w;
        acct += v.x * b.x + v.y * b.y + v.z * b.z + v.w * b.w;
    }
    ss[i] = accs;
    st[i] = acct;
}

// K2: per (e,h): p = exp(leaky_relu(ss[src,h] + st[trg,h])) -> pbuf (nt),
// atomicAdd into nsum[trg,h]; track running max concurrently.
// Identity: exp(lr-c)/(sum exp(lr-c)+eps) == exp(lr)/(sum exp(lr)+eps*e^c),
// so no max pre-pass is needed (validated r6: absmax identical to r3).
// r5-proven access pattern: 4 consecutive threads share one edge (same ei
// lines broadcast, same ss/st lines, pbuf stores coalesce to 16B).
__global__ void edge_exp_sum_kernel(const void* __restrict__ ei,
                                    const int* __restrict__ flag,
                                    const float* __restrict__ ss,
                                    const float* __restrict__ st,
                                    float* __restrict__ pbuf,
                                    float* __restrict__ nsum,
                                    unsigned* __restrict__ gmax,
                                    int E) {
    __shared__ float red[256];
    int is64 = *flag;
    int n4 = E * 4;
    int stride = gridDim.x * blockDim.x;
    float lmax = -__builtin_inff();
    for (int i = blockIdx.x * blockDim.x + threadIdx.x; i < n4; i += stride) {
        int e = i >> 2, h = i & 3;
        int trg = load_idx(ei, is64, e);
        int src = load_idx(ei, is64, (size_t)E + e);
        float s = ss[src * 4 + h] + st[trg * 4 + h];
        float lr = s > 0.f ? s : NEG_SLOPE * s;
        lmax = fmaxf(lmax, lr);
        float p = __expf(lr);
        __builtin_nontemporal_store(p, &pbuf[i]);
        atomicAdd(&nsum[trg * 4 + h], p);
    }
    red[threadIdx.x] = lmax;
    __syncthreads();
    for (int off = 128; off > 0; off >>= 1) {
        if (threadIdx.x < off)
            red[threadIdx.x] = fmaxf(red[threadIdx.x], red[threadIdx.x + off]);
        __syncthreads();
    }
    if (threadIdx.x == 0) atomicMax(gmax, fenc(red[0]));
}

// K3: fused gather + attention. 32 lanes per edge copy the 512B feature row
// (nt stores); lanes 0..3 additionally compute att[h] = p/(nsum[trg,h]+eps*e^c).
__global__ void gather_att_kernel(const void* __restrict__ ei,
                                  const int* __restrict__ flag,
                                  const f32x4* __restrict__ nf4,
                                  const float* __restrict__ pbuf,
                                  const float* __restrict__ nsum,
                                  const unsigned* __restrict__ gmax,
                                  float* __restrict__ att_out,
                                  f32x4* __restrict__ feat_out,
                                  int E) {
    int is64 = *flag;
    float de = EPSV * __expf(fdec(*gmax));
    int n = E * 32;
    int stride = gridDim.x * blockDim.x;
    for (int t = blockIdx.x * blockDim.x + threadIdx.x; t < n; t += stride) {
        int e = t >> 5, q = t & 31;
        int src = load_idx(ei, is64, (size_t)E + e);
        f32x4 v = nf4[(size_t)src * 32 + q];
        __builtin_nontemporal_store(v, &feat_out[(size_t)e * 32 + q]);
        if (q < 4) {
            int trg = load_idx(ei, is64, e);
            float p = __builtin_nontemporal_load(&pbuf[(size_t)e * 4 + q]);
            float a = p / (nsum[trg * 4 + q] + de);
            __builtin_nontemporal_store(a, &att_out[(size_t)e * 4 + q]);
        }
    }
}

// ---------- fallback (ws too small for pbuf): recompute pipeline ----------
__device__ __forceinline__ float edge_lr_rc(const void* ei, int is64,
                                            const float* ss, const float* st,
                                            int E, int e, int h, int* trg_out) {
    int trg = load_idx(ei, is64, e);
    int src = load_idx(ei, is64, (size_t)E + e);
    if (trg_out) *trg_out = trg;
    float s = ss[src * 4 + h] + st[trg * 4 + h];
    return s > 0.f ? s : NEG_SLOPE * s;
}

__global__ void edge_exp_sum_fb_kernel(const void* __restrict__ ei,
                                       const int* __restrict__ flag,
                                       const float* __restrict__ ss,
                                       const float* __restrict__ st,
                                       float* __restrict__ nsum,
                                       unsigned* __restrict__ gmax, int E) {
    __shared__ float red[256];
    int is64 = *flag;
    int n4 = E * 4;
    int stride = gridDim.x * blockDim.x;
    float lmax = -__builtin_inff();
    for (int i = blockIdx.x * blockDim.x + threadIdx.x; i < n4; i += stride) {
        int trg;
        float lr = edge_lr_rc(ei, is64, ss, st, E, i >> 2, i & 3, &trg);
        lmax = fmaxf(lmax, lr);
        atomicAdd(&nsum[trg * 4 + (i & 3)], __expf(lr));
    }
    red[threadIdx.x] = lmax;
    __syncthreads();
    for (int off = 128; off > 0; off >>= 1) {
        if (threadIdx.x < off)
            red[threadIdx.x] = fmaxf(red[threadIdx.x], red[threadIdx.x + off]);
        __syncthreads();
    }
    if (threadIdx.x == 0) atomicMax(gmax, fenc(red[0]));
}

__global__ void att_fb_kernel(const void* __restrict__ ei,
                              const int* __restrict__ flag,
                              const float* __restrict__ ss,
                              const float* __restrict__ st,
                              const unsigned* __restrict__ gmax,
                              const float* __restrict__ nsum,
                              float* __restrict__ out, int E) {
    int i = blockIdx.x * blockDim.x + threadIdx.x;
    if (i >= E * 4) return;
    int is64 = *flag;
    float de = EPSV * __expf(fdec(*gmax));
    int trg;
    float lr = edge_lr_rc(ei, is64, ss, st, E, i >> 2, i & 3, &trg);
    float a = __expf(lr) / (nsum[trg * 4 + (i & 3)] + de);
    __builtin_nontemporal_store(a, &out[i]);
}

__global__ void gather_feat_fb_kernel(const void* __restrict__ ei,
                                      const int* __restrict__ flag,
                                      const f32x4* __restrict__ nf4,
                                      f32x4* __restrict__ out4, int E) {
    int is64 = *flag;
    int n = E * 32;
    int stride = gridDim.x * blockDim.x;
    for (int t = blockIdx.x * blockDim.x + threadIdx.x; t < n; t += stride) {
        int e = t >> 5, q = t & 31;
        int src = load_idx(ei, is64, (size_t)E + e);
        f32x4 v = nf4[(size_t)src * 32 + q];
        __builtin_nontemporal_store(v, &out4[(size_t)e * 32 + q]);
    }
}

extern "C" void kernel_launch(void* const* d_in, const int* in_sizes, int n_in,
                              void* d_out, int out_size, void* d_ws, size_t ws_size,
                              hipStream_t stream) {
    const float* nf  = (const float*)d_in[0];
    const float* sfs = (const float*)d_in[1];
    const float* sft = (const float*)d_in[2];
    const void*  ei  = d_in[3];

    const int NH = in_sizes[0] / 32;   // N*H (F = 32)
    const int E  = in_sizes[3] / 2;

    float* out = (float*)d_out;
    float* ws  = (float*)d_ws;
    // Layout: ss[NH] | st[NH] | nsum[NH] | flag,gmax,pad,pad | pbuf[E*4]
    float*    ss    = ws;
    float*    st    = ws + NH;
    float*    nsum  = ws + 2 * (size_t)NH;
    int*      flag  = (int*)(ws + 3 * (size_t)NH);
    unsigned* gmax  = (unsigned*)(flag + 1);
    float*    pbuf  = ws + 3 * (size_t)NH + 4;

    size_t need = ((size_t)3 * NH + 4 + (size_t)E * 4) * 4;
    bool lean = ws_size >= need;

    const int B = 256;

    detect_idx_kernel<<<1, 256, 0, stream>>>((const unsigned*)ei, flag);

    node_scores_kernel<<<(NH + B - 1) / B, B, 0, stream>>>(nf, sfs, sft, ss, st,
                                                           nsum, gmax, NH);

    if (lean) {
        edge_exp_sum_kernel<<<2048, B, 0, stream>>>(ei, flag, ss, st, pbuf,
                                                    nsum, gmax, E);
        gather_att_kernel<<<4096, B, 0, stream>>>(ei, flag, (const f32x4*)nf,
                                                  pbuf, nsum, gmax,
                                                  out, (f32x4*)(out + (size_t)E * 4), E);
    } else {
        edge_exp_sum_fb_kernel<<<2048, B, 0, stream>>>(ei, flag, ss, st, nsum,
                                                       gmax, E);
        att_fb_kernel<<<(E * 4 + B - 1) / B, B, 0, stream>>>(ei, flag, ss, st,
                                                             gmax, nsum, out, E);
        gather_feat_fb_kernel<<<4096, B, 0, stream>>>(
            ei, flag, (const f32x4*)nf, (f32x4*)(out + (size_t)E * 4), E);
    }
}

// Round 8
// 256.032 us; speedup vs baseline: 1.3644x; 1.1112x over previous
//
#include <hip/hip_runtime.h>

#define NEG_SLOPE 0.2f
#define EPSV 1e-16f

typedef float f32x4 __attribute__((ext_vector_type(4)));

// Monotone f32 <-> u32 mapping so atomicMax(u32) implements float max.
__device__ __forceinline__ unsigned fenc(float f) {
    unsigned b = __float_as_uint(f);
    return b ^ ((b & 0x80000000u) ? 0xFFFFFFFFu : 0x80000000u);
}
__device__ __forceinline__ float fdec(unsigned u) {
    unsigned b = (u & 0x80000000u) ? (u ^ 0x80000000u) : ~u;
    return __uint_as_float(b);
}
#define FENC_NEG_INF 0x007FFFFFu   // fenc(-inf)

// Detect int64 vs int32 edge_index on device.
__global__ void detect_idx_kernel(const unsigned* __restrict__ ei32,
                                  int* __restrict__ flag) {
    __shared__ int anynz;
    if (threadIdx.x == 0) anynz = 0;
    __syncthreads();
    unsigned v = ei32[2 * threadIdx.x + 1];
    if (v != 0u) anynz = 1;
    __syncthreads();
    if (threadIdx.x == 0) *flag = (anynz ? 0 : 1);   // 1 => int64
}

__device__ __forceinline__ int load_idx(const void* ei, int is64, size_t k) {
    if (is64) return (int)__builtin_nontemporal_load(&((const long long*)ei)[k]);
    return __builtin_nontemporal_load(&((const int*)ei)[k]);
}

// K1: per-node logits per head; zero nsum (stride NS per node); init gmax.
__global__ void node_scores_kernel(const float* __restrict__ nf,
                                   const float* __restrict__ sfs,
                                   const float* __restrict__ sft,
                                   float* __restrict__ ss,
                                   float* __restrict__ st,
                                   float* __restrict__ nsum,
                                   unsigned* __restrict__ gmax,
                                   int NH, int nzero) {
    int i = blockIdx.x * blockDim.x + threadIdx.x;
    if (i >= NH) return;
    if (i == 0) *gmax = FENC_NEG_INF;
    for (int k = i; k < nzero; k += NH) nsum[k] = 0.f;
    int h = i & 3;
    const float4* __restrict__ row = (const float4*)(nf + (size_t)i * 32);
    const float4* __restrict__ as  = (const float4*)(sfs + h * 32);
    const float4* __restrict__ at  = (const float4*)(sft + h * 32);
    float accs = 0.f, acct = 0.f;
#pragma unroll
    for (int q = 0; q < 8; ++q) {
        float4 v = row[q];
        float4 a = as[q];
        float4 b = at[q];
        accs += v.x * a.x + v.y * a.y + v.z * a.z + v.w * a.w;
        acct += v.x * b.x + v.y * b.y + v.z * b.z + v.w * b.w;
    }
    ss[i] = accs;
    st[i] = acct;
}

// K2: combined kernel, block-role split.
//  - EVEN blocks: feature gather (write-BW-bound; 32 lanes x 16B per edge,
//    nt stores, loop kept pure -- r7 showed polluting this loop costs ~50us).
//  - ODD blocks: per-(e,h) p=exp(leaky_relu(.)) -> pbuf (nt), atomicAdd into
//    nsum[trg*NS+h] (atomic-latency-bound), track running max for the
//    eps-scale identity: exp(lr-c)/(S+eps) == exp(lr)/(S'+eps*e^c).
// The two roles use different pipes; co-residency overlaps their latencies.
__global__ void combined_kernel(const void* __restrict__ ei,
                                const int* __restrict__ flag,
                                const f32x4* __restrict__ nf4,
                                const float* __restrict__ ss,
                                const float* __restrict__ st,
                                float* __restrict__ pbuf,
                                float* __restrict__ nsum,
                                unsigned* __restrict__ gmax,
                                f32x4* __restrict__ feat_out,
                                int E, int NS) {
    __shared__ float red[256];
    int is64 = *flag;
    int vbid = blockIdx.x >> 1;
    int vstride = (gridDim.x >> 1) * blockDim.x;

    if ((blockIdx.x & 1) == 0) {
        // ---- gather role ----
        int n = E * 32;
        for (int t = vbid * blockDim.x + threadIdx.x; t < n; t += vstride) {
            int e = t >> 5, q = t & 31;
            int src = load_idx(ei, is64, (size_t)E + e);
            f32x4 v = nf4[(size_t)src * 32 + q];
            __builtin_nontemporal_store(v, &feat_out[(size_t)e * 32 + q]);
        }
    } else {
        // ---- exp/scatter role ----
        int n4 = E * 4;
        float lmax = -__builtin_inff();
        for (int i = vbid * blockDim.x + threadIdx.x; i < n4; i += vstride) {
            int e = i >> 2, h = i & 3;
            int trg = load_idx(ei, is64, e);
            int src = load_idx(ei, is64, (size_t)E + e);
            float s = ss[src * 4 + h] + st[trg * 4 + h];
            float lr = s > 0.f ? s : NEG_SLOPE * s;
            lmax = fmaxf(lmax, lr);
            float p = __expf(lr);
            __builtin_nontemporal_store(p, &pbuf[i]);
            atomicAdd(&nsum[(size_t)trg * NS + h], p);
        }
        red[threadIdx.x] = lmax;
        __syncthreads();
        for (int off = 128; off > 0; off >>= 1) {
            if (threadIdx.x < off)
                red[threadIdx.x] = fmaxf(red[threadIdx.x], red[threadIdx.x + off]);
            __syncthreads();
        }
        if (threadIdx.x == 0) atomicMax(gmax, fenc(red[0]));
    }
}

// K3: att = p / (nsum[trg] + eps*e^c); per-edge, float4 in/out (r5-proven).
__global__ void att_lean_kernel(const void* __restrict__ ei,
                                const int* __restrict__ flag,
                                const float* __restrict__ pbuf,
                                const float* __restrict__ nsum,
                                const unsigned* __restrict__ gmax,
                                float* __restrict__ out,
                                int E, int NS) {
    int is64 = *flag;
    float de = EPSV * __expf(fdec(*gmax));
    int stride = gridDim.x * blockDim.x;
    for (int e = blockIdx.x * blockDim.x + threadIdx.x; e < E; e += stride) {
        int trg = load_idx(ei, is64, e);
        f32x4 p = __builtin_nontemporal_load((const f32x4*)(pbuf + (size_t)e * 4));
        f32x4 d = *(const f32x4*)(nsum + (size_t)trg * NS);
        f32x4 a = p / (d + de);
        __builtin_nontemporal_store(a, (f32x4*)(out + (size_t)e * 4));
    }
}

// ---------- fallback (ws too small for pbuf): recompute pipeline ----------
__device__ __forceinline__ float edge_lr_rc(const void* ei, int is64,
                                            const float* ss, const float* st,
                                            int E, int e, int h, int* trg_out) {
    int trg = load_idx(ei, is64, e);
    int src = load_idx(ei, is64, (size_t)E + e);
    if (trg_out) *trg_out = trg;
    float s = ss[src * 4 + h] + st[trg * 4 + h];
    return s > 0.f ? s : NEG_SLOPE * s;
}

__global__ void edge_exp_sum_fb_kernel(const void* __restrict__ ei,
                                       const int* __restrict__ flag,
                                       const float* __restrict__ ss,
                                       const float* __restrict__ st,
                                       float* __restrict__ nsum,
                                       unsigned* __restrict__ gmax, int E) {
    __shared__ float red[256];
    int is64 = *flag;
    int n4 = E * 4;
    int stride = gridDim.x * blockDim.x;
    float lmax = -__builtin_inff();
    for (int i = blockIdx.x * blockDim.x + threadIdx.x; i < n4; i += stride) {
        int trg;
        float lr = edge_lr_rc(ei, is64, ss, st, E, i >> 2, i & 3, &trg);
        lmax = fmaxf(lmax, lr);
        atomicAdd(&nsum[trg * 4 + (i & 3)], __expf(lr));
    }
    red[threadIdx.x] = lmax;
    __syncthreads();
    for (int off = 128; off > 0; off >>= 1) {
        if (threadIdx.x < off)
            red[threadIdx.x] = fmaxf(red[threadIdx.x], red[threadIdx.x + off]);
        __syncthreads();
    }
    if (threadIdx.x == 0) atomicMax(gmax, fenc(red[0]));
}

__global__ void att_fb_kernel(const void* __restrict__ ei,
                              const int* __restrict__ flag,
                              const float* __restrict__ ss,
                              const float* __restrict__ st,
                              const unsigned* __restrict__ gmax,
                              const float* __restrict__ nsum,
                              float* __restrict__ out, int E) {
    int i = blockIdx.x * blockDim.x + threadIdx.x;
    if (i >= E * 4) return;
    int is64 = *flag;
    float de = EPSV * __expf(fdec(*gmax));
    int trg;
    float lr = edge_lr_rc(ei, is64, ss, st, E, i >> 2, i & 3, &trg);
    float a = __expf(lr) / (nsum[trg * 4 + (i & 3)] + de);
    __builtin_nontemporal_store(a, &out[i]);
}

__global__ void gather_feat_fb_kernel(const void* __restrict__ ei,
                                      const int* __restrict__ flag,
                                      const f32x4* __restrict__ nf4,
                                      f32x4* __restrict__ out4, int E) {
    int is64 = *flag;
    int n = E * 32;
    int stride = gridDim.x * blockDim.x;
    for (int t = blockIdx.x * blockDim.x + threadIdx.x; t < n; t += stride) {
        int e = t >> 5, q = t & 31;
        int src = load_idx(ei, is64, (size_t)E + e);
        f32x4 v = nf4[(size_t)src * 32 + q];
        __builtin_nontemporal_store(v, &out4[(size_t)e * 32 + q]);
    }
}

extern "C" void kernel_launch(void* const* d_in, const int* in_sizes, int n_in,
                              void* d_out, int out_size, void* d_ws, size_t ws_size,
                              hipStream_t stream) {
    const float* nf  = (const float*)d_in[0];
    const float* sfs = (const float*)d_in[1];
    const float* sft = (const float*)d_in[2];
    const void*  ei  = d_in[3];

    const int NH = in_sizes[0] / 32;   // N*H (F = 32)
    const int N  = NH / 4;
    const int E  = in_sizes[3] / 2;

    float* out = (float*)d_out;
    float* ws  = (float*)d_ws;

    const int B = 256;

    // Pick node stride for nsum: 16 floats (64B line per node, 4x less atomic
    // serialization) if ws fits, else 4. Layout:
    // ss[NH] | st[NH] | flag,gmax,pad,pad | pbuf[E*4] | nsum[N*NS]
    float*    ss   = ws;
    float*    st   = ws + NH;
    int*      flag = (int*)(ws + 2 * (size_t)NH);
    unsigned* gmax = (unsigned*)(flag + 1);
    float*    pbuf = ws + 2 * (size_t)NH + 4;
    float*    nsum = pbuf + (size_t)E * 4;

    int NS = 0;
    for (int cand = 16; cand >= 4; cand >>= 2) {
        size_t need = ((size_t)2 * NH + 4 + (size_t)E * 4 + (size_t)N * cand) * 4;
        if (ws_size >= need) { NS = cand; break; }
    }

    detect_idx_kernel<<<1, 256, 0, stream>>>((const unsigned*)ei, flag);

    if (NS > 0) {
        node_scores_kernel<<<(NH + B - 1) / B, B, 0, stream>>>(
            nf, sfs, sft, ss, st, nsum, gmax, NH, N * NS);
        combined_kernel<<<8192, B, 0, stream>>>(ei, flag, (const f32x4*)nf,
                                                ss, st, pbuf, nsum, gmax,
                                                (f32x4*)(out + (size_t)E * 4),
                                                E, NS);
        att_lean_kernel<<<2048, B, 0, stream>>>(ei, flag, pbuf, nsum, gmax,
                                                out, E, NS);
    } else {
        // minimal-ws fallback: nsum (stride 4) after gmax
        float* nsum_fb = (float*)(gmax + 1);
        node_scores_kernel<<<(NH + B - 1) / B, B, 0, stream>>>(
            nf, sfs, sft, ss, st, nsum_fb, gmax, NH, NH);
        edge_exp_sum_fb_kernel<<<2048, B, 0, stream>>>(ei, flag, ss, st,
                                                       nsum_fb, gmax, E);
        att_fb_kernel<<<(E * 4 + B - 1) / B, B, 0, stream>>>(ei, flag, ss, st,
                                                             gmax, nsum_fb, out, E);
        gather_feat_fb_kernel<<<4096, B, 0, stream>>>(
            ei, flag, (const f32x4*)nf, (f32x4*)(out + (size_t)E * 4), E);
    }
}

// Round 9
// 237.452 us; speedup vs baseline: 1.4711x; 1.0782x over previous
//
#include <hip/hip_runtime.h>
#include <hip/hip_bf16.h>

#define NEG_SLOPE 0.2f
#define EPSV 1e-16f

typedef float f32x4 __attribute__((ext_vector_type(4)));
typedef float f32x2 __attribute__((ext_vector_type(2)));
typedef short s16x2 __attribute__((ext_vector_type(2)));
typedef unsigned u32x2 __attribute__((ext_vector_type(2)));

// Monotone f32 <-> u32 mapping so atomicMax(u32) implements float max.
__device__ __forceinline__ unsigned fenc(float f) {
    unsigned b = __float_as_uint(f);
    return b ^ ((b & 0x80000000u) ? 0xFFFFFFFFu : 0x80000000u);
}
__device__ __forceinline__ float fdec(unsigned u) {
    unsigned b = (u & 0x80000000u) ? (u ^ 0x80000000u) : ~u;
    return __uint_as_float(b);
}
#define FENC_NEG_INF 0x007FFFFFu   // fenc(-inf)

__device__ __forceinline__ unsigned f32_to_bf16_rne(float f) {
    unsigned u = __float_as_uint(f);
    unsigned lsb = (u >> 16) & 1u;
    return (u + 0x7FFFu + lsb) >> 16;   // values are positive finite
}

// One packed atomic adds 2 bf16 lanes: native GLOBAL_ATOMIC_PK_ADD_BF16.
__device__ __forceinline__ void pk_atomic_add_bf16(unsigned* addr, float a, float b) {
#if __has_builtin(__builtin_amdgcn_global_atomic_fadd_v2bf16)
    s16x2 v;
    v.x = (short)f32_to_bf16_rne(a);
    v.y = (short)f32_to_bf16_rne(b);
    typedef __attribute__((address_space(1))) s16x2 gs16x2;
    __builtin_amdgcn_global_atomic_fadd_v2bf16((gs16x2*)(void*)addr, v);
#else
    // CAS fallback (not expected on gfx950)
    unsigned old = *addr, assumed;
    do {
        assumed = old;
        float lo = __uint_as_float((assumed & 0xFFFFu) << 16) + a;
        float hi = __uint_as_float(assumed & 0xFFFF0000u) + b;
        unsigned nv = (f32_to_bf16_rne(hi) << 16) | (f32_to_bf16_rne(lo) & 0xFFFFu);
        old = atomicCAS(addr, assumed, nv);
    } while (old != assumed);
#endif
}

// Detect int64 vs int32 edge_index on device.
__global__ void detect_idx_kernel(const unsigned* __restrict__ ei32,
                                  int* __restrict__ flag) {
    __shared__ int anynz;
    if (threadIdx.x == 0) anynz = 0;
    __syncthreads();
    unsigned v = ei32[2 * threadIdx.x + 1];
    if (v != 0u) anynz = 1;
    __syncthreads();
    if (threadIdx.x == 0) *flag = (anynz ? 0 : 1);   // 1 => int64
}

__device__ __forceinline__ int load_idx(const void* ei, int is64, size_t k) {
    if (is64) return (int)__builtin_nontemporal_load(&((const long long*)ei)[k]);
    return __builtin_nontemporal_load(&((const int*)ei)[k]);
}

// K1: per-node logits per head; zero pk nsum (nzero u32 words); init gmax.
__global__ void node_scores_kernel(const float* __restrict__ nf,
                                   const float* __restrict__ sfs,
                                   const float* __restrict__ sft,
                                   float* __restrict__ ss,
                                   float* __restrict__ st,
                                   unsigned* __restrict__ nsum_zero,
                                   unsigned* __restrict__ gmax,
                                   int NH, int nzero) {
    int i = blockIdx.x * blockDim.x + threadIdx.x;
    if (i >= NH) return;
    if (i == 0) *gmax = FENC_NEG_INF;
    for (int k = i; k < nzero; k += NH) nsum_zero[k] = 0u;
    int h = i & 3;
    const float4* __restrict__ row = (const float4*)(nf + (size_t)i * 32);
    const float4* __restrict__ as  = (const float4*)(sfs + h * 32);
    const float4* __restrict__ at  = (const float4*)(sft + h * 32);
    float accs = 0.f, acct = 0.f;
#pragma unroll
    for (int q = 0; q < 8; ++q) {
        float4 v = row[q];
        float4 a = as[q];
        float4 b = at[q];
        accs += v.x * a.x + v.y * a.y + v.z * a.z + v.w * a.w;
        acct += v.x * b.x + v.y * b.y + v.z * b.z + v.w * b.w;
    }
    ss[i] = accs;
    st[i] = acct;
}

// K2: per (edge, head-pair): p = exp(leaky_relu(ss+st)) for 2 heads -> pbuf
// (nt, 8B), ONE pk bf16 atomic into nsum_pk[trg*2+hp]; track running max.
// Identity (validated r6+): exp(lr-c)/(S+eps) == exp(lr)/(S'+eps*e^c) -> no
// max pre-pass; c only used in the final divide.
__global__ void edge_exp_sum_pk_kernel(const void* __restrict__ ei,
                                       const int* __restrict__ flag,
                                       const float* __restrict__ ss,
                                       const float* __restrict__ st,
                                       float* __restrict__ pbuf,
                                       unsigned* __restrict__ nsum_pk,
                                       unsigned* __restrict__ gmax,
                                       int E) {
    __shared__ float red[256];
    int is64 = *flag;
    int n2 = E * 2;
    int stride = gridDim.x * blockDim.x;
    float lmax = -__builtin_inff();
    for (int i = blockIdx.x * blockDim.x + threadIdx.x; i < n2; i += stride) {
        int e = i >> 1, hp = i & 1;
        int trg = load_idx(ei, is64, e);
        int src = load_idx(ei, is64, (size_t)E + e);
        f32x2 a = *(const f32x2*)(ss + (size_t)src * 4 + hp * 2);
        f32x2 b = *(const f32x2*)(st + (size_t)trg * 4 + hp * 2);
        float s0 = a.x + b.x, s1 = a.y + b.y;
        float lr0 = s0 > 0.f ? s0 : NEG_SLOPE * s0;
        float lr1 = s1 > 0.f ? s1 : NEG_SLOPE * s1;
        lmax = fmaxf(lmax, fmaxf(lr0, lr1));
        float p0 = __expf(lr0), p1 = __expf(lr1);
        f32x2 pv; pv.x = p0; pv.y = p1;
        __builtin_nontemporal_store(pv, (f32x2*)(pbuf + (size_t)e * 4 + hp * 2));
        pk_atomic_add_bf16(nsum_pk + (size_t)trg * 2 + hp, p0, p1);
    }
    red[threadIdx.x] = lmax;
    __syncthreads();
    for (int off = 128; off > 0; off >>= 1) {
        if (threadIdx.x < off)
            red[threadIdx.x] = fmaxf(red[threadIdx.x], red[threadIdx.x + off]);
        __syncthreads();
    }
    if (threadIdx.x == 0) atomicMax(gmax, fenc(red[0]));
}

// K3: att = p / (bf16_decode(nsum) + eps*e^c); per edge, float4 in/out.
__global__ void att_pk_kernel(const void* __restrict__ ei,
                              const int* __restrict__ flag,
                              const float* __restrict__ pbuf,
                              const unsigned* __restrict__ nsum_pk,
                              const unsigned* __restrict__ gmax,
                              float* __restrict__ out,
                              int E) {
    int is64 = *flag;
    float de = EPSV * __expf(fdec(*gmax));
    int stride = gridDim.x * blockDim.x;
    for (int e = blockIdx.x * blockDim.x + threadIdx.x; e < E; e += stride) {
        int trg = load_idx(ei, is64, e);
        u32x2 u = *(const u32x2*)(nsum_pk + (size_t)trg * 2);
        f32x4 d;
        d.x = __uint_as_float((u.x & 0xFFFFu) << 16);
        d.y = __uint_as_float(u.x & 0xFFFF0000u);
        d.z = __uint_as_float((u.y & 0xFFFFu) << 16);
        d.w = __uint_as_float(u.y & 0xFFFF0000u);
        f32x4 p = __builtin_nontemporal_load((const f32x4*)(pbuf + (size_t)e * 4));
        f32x4 a = p / (d + de);
        __builtin_nontemporal_store(a, (f32x4*)(out + (size_t)e * 4));
    }
}

// K4: feature gather; 32 lanes x 16B = 512B per edge, nt stores, loop pure.
__global__ void gather_feat_kernel(const void* __restrict__ ei,
                                   const int* __restrict__ flag,
                                   const f32x4* __restrict__ nf4,
                                   f32x4* __restrict__ out4, int E) {
    int is64 = *flag;
    int n = E * 32;
    int stride = gridDim.x * blockDim.x;
    for (int t = blockIdx.x * blockDim.x + threadIdx.x; t < n; t += stride) {
        int e = t >> 5, q = t & 31;
        int src = load_idx(ei, is64, (size_t)E + e);
        f32x4 v = nf4[(size_t)src * 32 + q];
        __builtin_nontemporal_store(v, &out4[(size_t)e * 32 + q]);
    }
}

// ---------- fallback (ws too small for pbuf): r8 recompute pipeline ----------
__device__ __forceinline__ float edge_lr_rc(const void* ei, int is64,
                                            const float* ss, const float* st,
                                            int E, int e, int h, int* trg_out) {
    int trg = load_idx(ei, is64, e);
    int src = load_idx(ei, is64, (size_t)E + e);
    if (trg_out) *trg_out = trg;
    float s = ss[src * 4 + h] + st[trg * 4 + h];
    return s > 0.f ? s : NEG_SLOPE * s;
}

__global__ void zero_fb_kernel(float* __restrict__ nsum, int n) {
    int i = blockIdx.x * blockDim.x + threadIdx.x;
    if (i < n) nsum[i] = 0.f;
}

__global__ void edge_exp_sum_fb_kernel(const void* __restrict__ ei,
                                       const int* __restrict__ flag,
                                       const float* __restrict__ ss,
                                       const float* __restrict__ st,
                                       float* __restrict__ nsum,
                                       unsigned* __restrict__ gmax, int E) {
    __shared__ float red[256];
    int is64 = *flag;
    int n4 = E * 4;
    int stride = gridDim.x * blockDim.x;
    float lmax = -__builtin_inff();
    for (int i = blockIdx.x * blockDim.x + threadIdx.x; i < n4; i += stride) {
        int trg;
        float lr = edge_lr_rc(ei, is64, ss, st, E, i >> 2, i & 3, &trg);
        lmax = fmaxf(lmax, lr);
        atomicAdd(&nsum[trg * 4 + (i & 3)], __expf(lr));
    }
    red[threadIdx.x] = lmax;
    __syncthreads();
    for (int off = 128; off > 0; off >>= 1) {
        if (threadIdx.x < off)
            red[threadIdx.x] = fmaxf(red[threadIdx.x], red[threadIdx.x + off]);
        __syncthreads();
    }
    if (threadIdx.x == 0) atomicMax(gmax, fenc(red[0]));
}

__global__ void att_fb_kernel(const void* __restrict__ ei,
                              const int* __restrict__ flag,
                              const float* __restrict__ ss,
                              const float* __restrict__ st,
                              const unsigned* __restrict__ gmax,
                              const float* __restrict__ nsum,
                              float* __restrict__ out, int E) {
    int i = blockIdx.x * blockDim.x + threadIdx.x;
    if (i >= E * 4) return;
    int is64 = *flag;
    float de = EPSV * __expf(fdec(*gmax));
    int trg;
    float lr = edge_lr_rc(ei, is64, ss, st, E, i >> 2, i & 3, &trg);
    float a = __expf(lr) / (nsum[trg * 4 + (i & 3)] + de);
    __builtin_nontemporal_store(a, &out[i]);
}

extern "C" void kernel_launch(void* const* d_in, const int* in_sizes, int n_in,
                              void* d_out, int out_size, void* d_ws, size_t ws_size,
                              hipStream_t stream) {
    const float* nf  = (const float*)d_in[0];
    const float* sfs = (const float*)d_in[1];
    const float* sft = (const float*)d_in[2];
    const void*  ei  = d_in[3];

    const int NH = in_sizes[0] / 32;   // N*H (F = 32)
    const int N  = NH / 4;
    const int E  = in_sizes[3] / 2;

    float* out = (float*)d_out;
    float* ws  = (float*)d_ws;

    // Layout: ss[NH] | st[NH] | flag,gmax,pad,pad | pbuf[E*4] | nsum_pk[N*2 u32]
    float*    ss      = ws;
    float*    st      = ws + NH;
    int*      flag    = (int*)(ws + 2 * (size_t)NH);
    unsigned* gmax    = (unsigned*)(flag + 1);
    float*    pbuf    = ws + 2 * (size_t)NH + 4;
    unsigned* nsum_pk = (unsigned*)(pbuf + (size_t)E * 4);

    size_t need = ((size_t)2 * NH + 4 + (size_t)E * 4 + (size_t)N * 2) * 4;
    bool lean = ws_size >= need;

    const int B = 256;

    detect_idx_kernel<<<1, 256, 0, stream>>>((const unsigned*)ei, flag);

    if (lean) {
        node_scores_kernel<<<(NH + B - 1) / B, B, 0, stream>>>(
            nf, sfs, sft, ss, st, nsum_pk, gmax, NH, N * 2);
        edge_exp_sum_pk_kernel<<<2048, B, 0, stream>>>(ei, flag, ss, st, pbuf,
                                                       nsum_pk, gmax, E);
        att_pk_kernel<<<2048, B, 0, stream>>>(ei, flag, pbuf, nsum_pk, gmax,
                                              out, E);
        gather_feat_kernel<<<4096, B, 0, stream>>>(
            ei, flag, (const f32x4*)nf, (f32x4*)(out + (size_t)E * 4), E);
    } else {
        // minimal-ws fallback: f32 nsum right after gmax
        float* nsum_fb = (float*)(gmax + 1);
        node_scores_kernel<<<(NH + B - 1) / B, B, 0, stream>>>(
            nf, sfs, sft, ss, st, (unsigned*)nsum_fb, gmax, NH, 0);
        zero_fb_kernel<<<(NH + B - 1) / B, B, 0, stream>>>(nsum_fb, NH);
        edge_exp_sum_fb_kernel<<<2048, B, 0, stream>>>(ei, flag, ss, st,
                                                       nsum_fb, gmax, E);
        att_fb_kernel<<<(E * 4 + B - 1) / B, B, 0, stream>>>(ei, flag, ss, st,
                                                             gmax, nsum_fb, out, E);
        gather_feat_kernel<<<4096, B, 0, stream>>>(
            ei, flag, (const f32x4*)nf, (f32x4*)(out + (size_t)E * 4), E);
    }
}